// Round 14
// baseline (1126.991 us; speedup 1.0000x reference)
//
#include <hip/hip_runtime.h>

#define N_WORDS 262144
#define N_TAGS  512
#define BDIM    768
#define MDIM    128
#define KS      32              // K per slice
#define NSL     (BDIM / KS)     // 24 slices
#define BW      32              // words per panel
#define NPAN    8               // panels per block

typedef __attribute__((ext_vector_type(8))) short  bf16x8;
typedef __attribute__((ext_vector_type(4))) float  f32x4;
typedef __attribute__((ext_vector_type(2))) float  f32x2;

// async global->LDS, 16B per lane; dest base must be wave-uniform
#define GLOAD16(ldsdst, gsrc) __builtin_amdgcn_global_load_lds( \
    (const __attribute__((address_space(1))) unsigned int*)(gsrc), \
    (__attribute__((address_space(3))) unsigned int*)(ldsdst), 16, 0, 0)

// RNE fp32 -> bf16 (inputs finite)
__device__ inline unsigned bf16_1(float a) {
    union { float f; unsigned u; } ua; ua.f = a;
    unsigned x = ua.u;
    x += 0x7fffu + ((x >> 16) & 1u);
    return x >> 16;
}
__device__ inline unsigned bf16_2(float a, float b) {
    union { float f; unsigned u; } ua, ub; ua.f = a; ub.f = b;
    unsigned x = ua.u, y = ub.u;
    x += 0x7fffu + ((x >> 16) & 1u);
    y += 0x7fffu + ((y >> 16) & 1u);
    return (x >> 16) | (y & 0xffff0000u);
}
__device__ inline f32x2 ntld2(const float* p) {
    return __builtin_nontemporal_load(reinterpret_cast<const f32x2*>(p));
}

// ---------------------------------------------------------------------------
__global__ __launch_bounds__(128) void tags_kernel(
    const float* __restrict__ tags_embed, const float* __restrict__ tags_W,
    const float* __restrict__ tags_b, const float* __restrict__ words_b,
    unsigned short* __restrict__ Tbf, float* __restrict__ cvec)
{
    __shared__ __align__(16) float sE[BDIM];
    __shared__ float red[128];
    const int t = blockIdx.x;
    const int m = threadIdx.x;

    for (int i = m; i < BDIM; i += 128) sE[i] = tags_embed[(size_t)t * BDIM + i];
    __syncthreads();

    float acc = tags_b[m];
    const float* Wr = tags_W + (size_t)m * BDIM;
    #pragma unroll 8
    for (int b = 0; b < BDIM; b += 4) {
        float4 w4 = *reinterpret_cast<const float4*>(Wr + b);
        float4 e4 = *reinterpret_cast<const float4*>(&sE[b]);
        acc += w4.x * e4.x + w4.y * e4.y + w4.z * e4.z + w4.w * e4.w;
    }
    Tbf[(size_t)t * MDIM + m] = (unsigned short)bf16_1(2.0f * acc);

    red[m] = acc * (2.0f * words_b[m] - acc);
    __syncthreads();
    for (int s = 64; s > 0; s >>= 1) {
        if (m < s) red[m] += red[m + s];
        __syncthreads();
    }
    if (m == 0) cvec[t] = red[0];
}

__global__ __launch_bounds__(256) void wt_kernel(
    const float* __restrict__ W, unsigned short* __restrict__ Wtbf)
{
    __shared__ float sT[32][33];
    const int bm = blockIdx.x & 3, bk = blockIdx.x >> 2;
    const int m0 = bm * 32, k0 = bk * 32;
    const int r = threadIdx.x >> 3, c = threadIdx.x & 7;

    f32x4 w4 = *reinterpret_cast<const f32x4*>(W + (size_t)(m0 + r) * BDIM + k0 + c * 4);
    sT[r][c * 4 + 0] = w4.x;  sT[r][c * 4 + 1] = w4.y;
    sT[r][c * 4 + 2] = w4.z;  sT[r][c * 4 + 3] = w4.w;
    __syncthreads();

    unsigned lo = bf16_2(sT[c * 4 + 0][r], sT[c * 4 + 1][r]);
    unsigned hi = bf16_2(sT[c * 4 + 2][r], sT[c * 4 + 3][r]);
    unsigned long long p = ((unsigned long long)hi << 32) | lo;
    *reinterpret_cast<unsigned long long*>(Wtbf + (size_t)(k0 + r) * MDIM + m0 + c * 4) = p;
}

// GtSl[s][tag][k%32], slice-major
__global__ __launch_bounds__(64) void gt_kernel(
    const unsigned short* __restrict__ Wtbf, const unsigned short* __restrict__ Tbf,
    unsigned short* __restrict__ GtSl)
{
    const int kt = blockIdx.x % 48, tg = blockIdx.x / 48;
    const int k0 = kt * 16, t0 = tg * 64;
    const int n = threadIdx.x & 15, q = threadIdx.x >> 4;

    bf16x8 a[4];
    #pragma unroll
    for (int ks = 0; ks < 4; ++ks)
        a[ks] = *reinterpret_cast<const bf16x8*>(
            Wtbf + (size_t)(k0 + n) * MDIM + ks * 32 + q * 8);

    const int s2  = kt >> 1;
    const int off = (kt & 1) * 16 + 4 * q;

    #pragma unroll
    for (int tt = 0; tt < 4; ++tt) {
        f32x4 acc = (f32x4){0.f, 0.f, 0.f, 0.f};
        #pragma unroll
        for (int ks = 0; ks < 4; ++ks) {
            bf16x8 b = *reinterpret_cast<const bf16x8*>(
                Tbf + (size_t)(t0 + tt * 16 + n) * MDIM + ks * 32 + q * 8);
            acc = __builtin_amdgcn_mfma_f32_16x16x32_bf16(a[ks], b, acc, 0, 0, 0);
        }
        unsigned lo = bf16_2(acc.x, acc.y);
        unsigned hi = bf16_2(acc.z, acc.w);
        unsigned long long p = ((unsigned long long)hi << 32) | lo;
        *reinterpret_cast<unsigned long long*>(
            GtSl + (size_t)s2 * (N_TAGS * KS) + (size_t)(t0 + tt * 16 + n) * KS + off) = p;
    }
}

// ---------------------------------------------------------------------------
// main: dual-accumulator pipelined panels. 1024 blocks x 512 thr (8 waves).
// Panel = 32 words x 512 tags; wave v = tags v*64..+63. While panel p's
// K-loop runs, slices 0..7 each emit one (lp,pp) store-pair of panel p-1.
// Per slice: [4 Gt DMA][NT E-load][2 stores] -> vmcnt(3) barrier (stores
// fly, DMAs retired). First K-loop: no stores (vmcnt(1) = r7). Last panel
// bursts.
// ---------------------------------------------------------------------------
__device__ __forceinline__ const float* pro(
    const float* __restrict__ embed, const unsigned short* __restrict__ GtSl,
    unsigned short* sG, unsigned short* sE,
    int v, int lane, int we, int kp, int w0p, f32x2& eOld)
{
    const float* eSrc = embed + (size_t)(w0p + we) * BDIM + kp * 2;
    #pragma unroll
    for (int r = 0; r < 4; ++r)
        GLOAD16(sG + (r * 8 + v) * 512,
                GtSl + (size_t)((r * 8 + v) * 64 + lane) * 8);
    f32x2 e0 = ntld2(eSrc);
    eOld = ntld2(eSrc + KS);
    *reinterpret_cast<unsigned*>(sE + we * KS + kp * 2) = bf16_2(e0.x, e0.y);
    asm volatile("s_waitcnt vmcnt(1) lgkmcnt(0)\n\ts_barrier" ::: "memory");
    return eSrc;
}

template<bool DOST>
__device__ __forceinline__ void kloop(
    const float* __restrict__ eSrc, const unsigned short* __restrict__ GtSl,
    unsigned short* sG, unsigned short* sE,
    const int v, const int lane, const int n, const int q,
    const int we, const int kp, f32x2& eOld,
    f32x4 (&acc)[4][2],
    const f32x4 (&accP)[4][2], const float (&negP)[2],
    const unsigned long long (&offP)[2],
    float* __restrict__ out_logp, float* __restrict__ out_p)
{
    #pragma unroll
    for (int mt = 0; mt < 4; ++mt) {
        acc[mt][0] = (f32x4){0.f, 0.f, 0.f, 0.f};
        acc[mt][1] = (f32x4){0.f, 0.f, 0.f, 0.f};
    }

    // slices 0..7: unrolled (static store indices)
    #pragma unroll
    for (int s = 0; s < 8; ++s) {
        const int nxt = (s & 1) ^ 1;
        #pragma unroll
        for (int r = 0; r < 4; ++r)
            GLOAD16(sG + nxt * (N_TAGS * KS) + (r * 8 + v) * 512,
                    GtSl + (size_t)(s + 1) * (N_TAGS * KS)
                         + (size_t)((r * 8 + v) * 64 + lane) * 8);
        f32x2 eN = ntld2(eSrc + (s + 2) * KS);
        *reinterpret_cast<unsigned*>(sE + nxt * (BW * KS) + we * KS + kp * 2) =
            bf16_2(eOld.x, eOld.y);
        if constexpr (DOST) {
            const int smt = s >> 1, swt = s & 1;
            f32x4 d = accP[smt][swt] - negP[swt];
            *reinterpret_cast<f32x4*>(out_logp + offP[swt] + smt * 16) = d;
            f32x4 e;
            e.x = __expf(d.x); e.y = __expf(d.y);
            e.z = __expf(d.z); e.w = __expf(d.w);
            *reinterpret_cast<f32x4*>(out_p + offP[swt] + smt * 16) = e;
        }
        {
            const unsigned short* sGc = sG + (s & 1) * (N_TAGS * KS);
            const unsigned short* sEc = sE + (s & 1) * (BW * KS);
            bf16x8 b0 = *reinterpret_cast<const bf16x8*>(sEc + n * KS + q * 8);
            bf16x8 b1 = *reinterpret_cast<const bf16x8*>(sEc + (16 + n) * KS + q * 8);
            #pragma unroll
            for (int mt = 0; mt < 4; ++mt) {
                bf16x8 a = *reinterpret_cast<const bf16x8*>(
                    sGc + (v * 64 + mt * 16 + n) * KS + q * 8);
                acc[mt][0] = __builtin_amdgcn_mfma_f32_16x16x32_bf16(a, b0, acc[mt][0], 0, 0, 0);
                acc[mt][1] = __builtin_amdgcn_mfma_f32_16x16x32_bf16(a, b1, acc[mt][1], 0, 0, 0);
            }
        }
        if constexpr (DOST)
            asm volatile("s_waitcnt vmcnt(3) lgkmcnt(0)\n\ts_barrier" ::: "memory");
        else
            asm volatile("s_waitcnt vmcnt(1) lgkmcnt(0)\n\ts_barrier" ::: "memory");
        eOld = eN;
    }

    // slices 8..23: runtime (r7 pattern)
    int cur = 0;
    #pragma unroll 1
    for (int s = 8; s < NSL; ++s) {
        const int nxt = cur ^ 1;
        if (s + 1 < NSL) {
            #pragma unroll
            for (int r = 0; r < 4; ++r)
                GLOAD16(sG + nxt * (N_TAGS * KS) + (r * 8 + v) * 512,
                        GtSl + (size_t)(s + 1) * (N_TAGS * KS)
                             + (size_t)((r * 8 + v) * 64 + lane) * 8);
        }
        f32x2 eN;
        if (s + 2 < NSL) eN = ntld2(eSrc + (s + 2) * KS);
        if (s + 1 < NSL)
            *reinterpret_cast<unsigned*>(sE + nxt * (BW * KS) + we * KS + kp * 2) =
                bf16_2(eOld.x, eOld.y);
        {
            const unsigned short* sGc = sG + cur * (N_TAGS * KS);
            const unsigned short* sEc = sE + cur * (BW * KS);
            bf16x8 b0 = *reinterpret_cast<const bf16x8*>(sEc + n * KS + q * 8);
            bf16x8 b1 = *reinterpret_cast<const bf16x8*>(sEc + (16 + n) * KS + q * 8);
            #pragma unroll
            for (int mt = 0; mt < 4; ++mt) {
                bf16x8 a = *reinterpret_cast<const bf16x8*>(
                    sGc + (v * 64 + mt * 16 + n) * KS + q * 8);
                acc[mt][0] = __builtin_amdgcn_mfma_f32_16x16x32_bf16(a, b0, acc[mt][0], 0, 0, 0);
                acc[mt][1] = __builtin_amdgcn_mfma_f32_16x16x32_bf16(a, b1, acc[mt][1], 0, 0, 0);
            }
        }
        if (s + 2 < NSL) {
            asm volatile("s_waitcnt vmcnt(1) lgkmcnt(0)\n\ts_barrier" ::: "memory");
        } else if (s + 1 < NSL) {
            asm volatile("s_waitcnt vmcnt(0) lgkmcnt(0)\n\ts_barrier" ::: "memory");
        }
        eOld = eN;
        cur = nxt;
    }
}

__device__ __forceinline__ void softmax_panel(
    f32x4 (&acc)[4][2], const float* __restrict__ cvec,
    float* sMx, float* sSm,
    const int v, const int n, const int q, const int w0p,
    float (&neg)[2], unsigned long long (&off)[2])
{
    #pragma unroll
    for (int mt = 0; mt < 4; ++mt) {
        f32x4 c4 = *reinterpret_cast<const f32x4*>(cvec + v * 64 + mt * 16 + 4 * q);
        acc[mt][0] += c4;
        acc[mt][1] += c4;
    }
    float mx[2], sm[2];
    #pragma unroll
    for (int wt = 0; wt < 2; ++wt) {
        float m = -3.0e38f;
        #pragma unroll
        for (int mt = 0; mt < 4; ++mt)
            m = fmaxf(m, fmaxf(fmaxf(acc[mt][wt].x, acc[mt][wt].y),
                               fmaxf(acc[mt][wt].z, acc[mt][wt].w)));
        m = fmaxf(m, __shfl_xor(m, 16, 64));
        m = fmaxf(m, __shfl_xor(m, 32, 64));
        mx[wt] = m;
        float s = 0.f;
        #pragma unroll
        for (int mt = 0; mt < 4; ++mt)
            s += __expf(acc[mt][wt].x - m) + __expf(acc[mt][wt].y - m)
               + __expf(acc[mt][wt].z - m) + __expf(acc[mt][wt].w - m);
        s += __shfl_xor(s, 16, 64);
        s += __shfl_xor(s, 32, 64);
        sm[wt] = s;
    }
    if (q == 0) {
        sMx[v * 32 + n]      = mx[0];
        sMx[v * 32 + 16 + n] = mx[1];
        sSm[v * 32 + n]      = sm[0];
        sSm[v * 32 + 16 + n] = sm[1];
    }
    __syncthreads();
    #pragma unroll
    for (int wt = 0; wt < 2; ++wt) {
        const int wd = wt * 16 + n;
        float M = sMx[wd];
        #pragma unroll
        for (int u = 1; u < 8; ++u) M = fmaxf(M, sMx[u * 32 + wd]);
        float S = 0.f;
        #pragma unroll
        for (int u = 0; u < 8; ++u) S += sSm[u * 32 + wd] * __expf(sMx[u * 32 + wd] - M);
        neg[wt] = M + __logf(S);
        off[wt] = (unsigned long long)(w0p + wd) * N_TAGS + v * 64 + 4 * q;
    }
}

__global__ __launch_bounds__(512, 4) void main_kernel(
    const float* __restrict__ embed,                 // [N][768] fp32
    const unsigned short* __restrict__ GtSl,         // [24][512][32] bf16
    const float* __restrict__ cvec,                  // [512] fp32
    float* __restrict__ out_logp, float* __restrict__ out_p)
{
    __shared__ __align__(16) unsigned short sG[2 * N_TAGS * KS];  // 64 KB
    __shared__ __align__(16) unsigned short sE[2 * BW * KS];      // 4 KB
    __shared__ float sMx[8 * 32];
    __shared__ float sSm[8 * 32];

    const int tid  = threadIdx.x;
    const int lane = tid & 63;
    const int v    = tid >> 6;
    const int n    = lane & 15;
    const int q    = lane >> 4;
    const int we   = tid >> 4;       // staging word 0..31
    const int kp   = tid & 15;       // staging 2-float granule
    const int w0base = blockIdx.x * (BW * NPAN);

    f32x4 accA[4][2], accB[4][2];
    float negA[2], negB[2] = {0.f, 0.f};
    unsigned long long offA[2], offB[2] = {0ull, 0ull};
    f32x2 eOld;

    const float* eSrc = pro(embed, GtSl, sG, sE, v, lane, we, kp, w0base, eOld);
    kloop<false>(eSrc, GtSl, sG, sE, v, lane, n, q, we, kp, eOld,
                 accA, accB, negB, offB, out_logp, out_p);
    softmax_panel(accA, cvec, sMx, sSm, v, n, q, w0base, negA, offA);
    eSrc = pro(embed, GtSl, sG, sE, v, lane, we, kp, w0base + BW, eOld);

    #pragma unroll 1
    for (int pp = 0; pp < 3; ++pp) {
        const int p1 = 2 * pp + 1, p2 = 2 * pp + 2;
        kloop<true>(eSrc, GtSl, sG, sE, v, lane, n, q, we, kp, eOld,
                    accB, accA, negA, offA, out_logp, out_p);
        softmax_panel(accB, cvec, sMx, sSm, v, n, q, w0base + p1 * BW, negB, offB);
        eSrc = pro(embed, GtSl, sG, sE, v, lane, we, kp, w0base + p2 * BW, eOld);
        kloop<true>(eSrc, GtSl, sG, sE, v, lane, n, q, we, kp, eOld,
                    accA, accB, negB, offB, out_logp, out_p);
        softmax_panel(accA, cvec, sMx, sSm, v, n, q, w0base + p2 * BW, negA, offA);
        eSrc = pro(embed, GtSl, sG, sE, v, lane, we, kp, w0base + (p2 + 1) * BW, eOld);
    }
    kloop<true>(eSrc, GtSl, sG, sE, v, lane, n, q, we, kp, eOld,
                accB, accA, negA, offA, out_logp, out_p);
    softmax_panel(accB, cvec, sMx, sSm, v, n, q, w0base + 7 * BW, negB, offB);

    // final burst: panel 7
    #pragma unroll
    for (int mt = 0; mt < 4; ++mt)
        #pragma unroll
        for (int wt = 0; wt < 2; ++wt) {
            f32x4 d = accB[mt][wt] - negB[wt];
            *reinterpret_cast<f32x4*>(out_logp + offB[wt] + mt * 16) = d;
            f32x4 e;
            e.x = __expf(d.x); e.y = __expf(d.y);
            e.z = __expf(d.z); e.w = __expf(d.w);
            *reinterpret_cast<f32x4*>(out_p + offB[wt] + mt * 16) = e;
        }
}

extern "C" void kernel_launch(void* const* d_in, const int* in_sizes, int n_in,
                              void* d_out, int out_size, void* d_ws, size_t ws_size,
                              hipStream_t stream) {
    const float* tags_embed  = (const float*)d_in[0];
    const float* words_embed = (const float*)d_in[1];
    const float* tags_W      = (const float*)d_in[2];
    const float* tags_b      = (const float*)d_in[3];
    const float* words_W     = (const float*)d_in[4];
    const float* words_b     = (const float*)d_in[5];

    float* out_logp = (float*)d_out;
    float* out_p    = out_logp + (size_t)N_WORDS * N_TAGS;

    // ws: Tbf [512][128] bf16 | cvec [512] f32 | Wtbf [768][128] bf16 |
    //     GtSl [24][512][32] bf16
    unsigned short* Tbf  = (unsigned short*)d_ws;
    float*          cvec = (float*)(Tbf + (size_t)N_TAGS * MDIM);
    unsigned short* Wtbf = (unsigned short*)(cvec + N_TAGS);
    unsigned short* GtSl = Wtbf + (size_t)BDIM * MDIM;

    tags_kernel<<<N_TAGS, 128, 0, stream>>>(tags_embed, tags_W, tags_b, words_b, Tbf, cvec);
    wt_kernel<<<96, 256, 0, stream>>>(words_W, Wtbf);
    gt_kernel<<<384, 64, 0, stream>>>(Wtbf, Tbf, GtSl);
    main_kernel<<<N_WORDS / (BW * NPAN), 512, 0, stream>>>(
        words_embed, GtSl, cvec, out_logp, out_p);
}

// Round 15
// 572.668 us; speedup vs baseline: 1.9680x; 1.9680x over previous
//
#include <hip/hip_runtime.h>

#define N_WORDS 262144
#define N_TAGS  512
#define BDIM    768
#define MDIM    128
#define KS      32              // K per slice
#define NSL     (BDIM / KS)     // 24 slices
#define BW      64              // words per block

typedef __attribute__((ext_vector_type(8))) short  bf16x8;
typedef __attribute__((ext_vector_type(4))) float  f32x4;

// async global->LDS, 16B per lane; dest base must be wave-uniform
#define GLOAD16(ldsdst, gsrc) __builtin_amdgcn_global_load_lds( \
    (const __attribute__((address_space(1))) unsigned int*)(gsrc), \
    (__attribute__((address_space(3))) unsigned int*)(ldsdst), 16, 0, 0)

// RNE fp32 -> bf16 (inputs finite)
__device__ inline unsigned bf16_1(float a) {
    union { float f; unsigned u; } ua; ua.f = a;
    unsigned x = ua.u;
    x += 0x7fffu + ((x >> 16) & 1u);
    return x >> 16;
}
// pack two fp32 -> (bf16(b)<<16)|bf16(a)
__device__ inline unsigned bf16_2(float a, float b) {
    union { float f; unsigned u; } ua, ub; ua.f = a; ub.f = b;
    unsigned x = ua.u, y = ub.u;
    x += 0x7fffu + ((x >> 16) & 1u);
    y += 0x7fffu + ((y >> 16) & 1u);
    return (x >> 16) | (y & 0xffff0000u);
}

// non-temporal streaming load (embed is read-once; keep it out of L2)
__device__ inline f32x4 ntld4(const float* p) {
    return __builtin_nontemporal_load(reinterpret_cast<const f32x4*>(p));
}

// ---------------------------------------------------------------------------
// tags: Tm[t][m] = tags_embed[t].tags_W[m] + tags_b[m]  (fp32)
//   Tbf[t][m] = bf16(2*Tm)                  (k-contiguous rows)
//   cvec[t]   = 2*words_b.Tm_t - ||Tm_t||^2 (fp32)
// ---------------------------------------------------------------------------
__global__ __launch_bounds__(128) void tags_kernel(
    const float* __restrict__ tags_embed, const float* __restrict__ tags_W,
    const float* __restrict__ tags_b, const float* __restrict__ words_b,
    unsigned short* __restrict__ Tbf, float* __restrict__ cvec)
{
    __shared__ __align__(16) float sE[BDIM];
    __shared__ float red[128];
    const int t = blockIdx.x;
    const int m = threadIdx.x;

    for (int i = m; i < BDIM; i += 128) sE[i] = tags_embed[(size_t)t * BDIM + i];
    __syncthreads();

    float acc = tags_b[m];
    const float* Wr = tags_W + (size_t)m * BDIM;
    #pragma unroll 8
    for (int b = 0; b < BDIM; b += 4) {
        float4 w4 = *reinterpret_cast<const float4*>(Wr + b);
        float4 e4 = *reinterpret_cast<const float4*>(&sE[b]);
        acc += w4.x * e4.x + w4.y * e4.y + w4.z * e4.z + w4.w * e4.w;
    }
    Tbf[(size_t)t * MDIM + m] = (unsigned short)bf16_1(2.0f * acc);

    red[m] = acc * (2.0f * words_b[m] - acc);
    __syncthreads();
    for (int s = 64; s > 0; s >>= 1) {
        if (m < s) red[m] += red[m + s];
        __syncthreads();
    }
    if (m == 0) cvec[t] = red[0];
}

// ---------------------------------------------------------------------------
// wt: Wtbf[768][128] bf16 = transpose(words_W fp32 [128][768])
// ---------------------------------------------------------------------------
__global__ __launch_bounds__(256) void wt_kernel(
    const float* __restrict__ W, unsigned short* __restrict__ Wtbf)
{
    __shared__ float sT[32][33];
    const int bm = blockIdx.x & 3, bk = blockIdx.x >> 2;
    const int m0 = bm * 32, k0 = bk * 32;
    const int r = threadIdx.x >> 3, c = threadIdx.x & 7;

    f32x4 w4 = *reinterpret_cast<const f32x4*>(W + (size_t)(m0 + r) * BDIM + k0 + c * 4);
    sT[r][c * 4 + 0] = w4.x;  sT[r][c * 4 + 1] = w4.y;
    sT[r][c * 4 + 2] = w4.z;  sT[r][c * 4 + 3] = w4.w;
    __syncthreads();

    unsigned lo = bf16_2(sT[c * 4 + 0][r], sT[c * 4 + 1][r]);
    unsigned hi = bf16_2(sT[c * 4 + 2][r], sT[c * 4 + 3][r]);
    unsigned long long p = ((unsigned long long)hi << 32) | lo;
    *reinterpret_cast<unsigned long long*>(Wtbf + (size_t)(k0 + r) * MDIM + m0 + c * 4) = p;
}

// ---------------------------------------------------------------------------
// gt: G[tag][k] = sum_m Wt[k][m] * (2T)[tag][m]  -> stored SLICE-MAJOR:
//     GtSl[s][tag][k%32], s = k/32.
// ---------------------------------------------------------------------------
__global__ __launch_bounds__(64) void gt_kernel(
    const unsigned short* __restrict__ Wtbf, const unsigned short* __restrict__ Tbf,
    unsigned short* __restrict__ GtSl)
{
    const int kt = blockIdx.x % 48, tg = blockIdx.x / 48;
    const int k0 = kt * 16, t0 = tg * 64;
    const int n = threadIdx.x & 15, q = threadIdx.x >> 4;

    bf16x8 a[4];
    #pragma unroll
    for (int ks = 0; ks < 4; ++ks)
        a[ks] = *reinterpret_cast<const bf16x8*>(
            Wtbf + (size_t)(k0 + n) * MDIM + ks * 32 + q * 8);

    const int s2  = kt >> 1;
    const int off = (kt & 1) * 16 + 4 * q;     // k offset within slice

    #pragma unroll
    for (int tt = 0; tt < 4; ++tt) {
        f32x4 acc = (f32x4){0.f, 0.f, 0.f, 0.f};
        #pragma unroll
        for (int ks = 0; ks < 4; ++ks) {
            bf16x8 b = *reinterpret_cast<const bf16x8*>(
                Tbf + (size_t)(t0 + tt * 16 + n) * MDIM + ks * 32 + q * 8);
            acc = __builtin_amdgcn_mfma_f32_16x16x32_bf16(a[ks], b, acc, 0, 0, 0);
        }
        unsigned lo = bf16_2(acc.x, acc.y);
        unsigned hi = bf16_2(acc.z, acc.w);
        unsigned long long p = ((unsigned long long)hi << 32) | lo;
        *reinterpret_cast<unsigned long long*>(
            GtSl + (size_t)s2 * (N_TAGS * KS) + (size_t)(t0 + tt * 16 + n) * KS + off) = p;
    }
}

// ---------------------------------------------------------------------------
// main: r7 K-sliced LDS GEMM + fused softmax, counted-vmcnt pipeline,
// with NON-TEMPORAL embed loads (read-once stream stays out of L2).
// 4096 blocks x 512 thr (8 waves). Block = 64 words x 512 tags.
// Per slice s: issue [4x GLOAD Gt(s+1), 1x NT E-load(s+2)] -> compute s ->
//   s_waitcnt vmcnt(1) lgkmcnt(0); s_barrier   (E-load stays in flight).
// ---------------------------------------------------------------------------
__global__ __launch_bounds__(512, 4) void main_kernel(
    const float* __restrict__ embed,                 // [N][768] fp32
    const unsigned short* __restrict__ GtSl,         // [24][512][32] bf16
    const float* __restrict__ cvec,                  // [512] fp32
    float* __restrict__ out_logp, float* __restrict__ out_p)
{
    __shared__ __align__(16) unsigned short sG[2 * N_TAGS * KS];  // 64 KB
    __shared__ __align__(16) unsigned short sE[2 * BW * KS];      // 8 KB
    __shared__ float sMx[8][BW];
    __shared__ float sSm[8][BW];

    const int tid  = threadIdx.x;
    const int lane = tid & 63;
    const int v    = tid >> 6;       // wave 0..7
    const int n    = lane & 15;
    const int q    = lane >> 4;
    const int we   = tid >> 3;       // staging word 0..63
    const int kp   = tid & 7;        // staging k-part
    const int w0   = blockIdx.x * BW;

    const float* eSrc = embed + (size_t)(w0 + we) * BDIM + kp * 4;

    // ---- prologue: E(0) -> LDS, Gt(0) DMA, E(1) in flight across barrier ----
    f32x4 eOld;
    {
        f32x4 e0 = ntld4(eSrc);                                    // E slice 0
        #pragma unroll
        for (int r = 0; r < 4; ++r)
            GLOAD16(sG + (r * 8 + v) * 512,
                    GtSl + (size_t)((r * 8 + v) * 64 + lane) * 8);
        eOld = ntld4(eSrc + KS);                                   // E slice 1
        unsigned lo = bf16_2(e0.x, e0.y), hi = bf16_2(e0.z, e0.w); // compiler waits e0
        *reinterpret_cast<unsigned long long*>(sE + we * KS + kp * 4) =
            ((unsigned long long)hi << 32) | lo;
        // retire the 4 Gt DMAs; keep E(1) in flight; drain LDS writes
        asm volatile("s_waitcnt vmcnt(1) lgkmcnt(0)\n\ts_barrier" ::: "memory");
    }

    f32x4 acc[4][4];
    #pragma unroll
    for (int mt = 0; mt < 4; ++mt)
        #pragma unroll
        for (int wt = 0; wt < 4; ++wt)
            acc[mt][wt] = (f32x4){0.f, 0.f, 0.f, 0.f};

    int cur = 0;
    for (int s = 0; s < NSL; ++s) {
        const int nxt = cur ^ 1;

        // issue next Gt slice DMA first (so vmcnt(1) keeps only the E-load)
        if (s + 1 < NSL) {
            #pragma unroll
            for (int r = 0; r < 4; ++r)
                GLOAD16(sG + nxt * (N_TAGS * KS) + (r * 8 + v) * 512,
                        GtSl + (size_t)(s + 1) * (N_TAGS * KS)
                             + (size_t)((r * 8 + v) * 64 + lane) * 8);
        }
        // issue NT E-load for slice s+2 (consumed via LDS at s+2)
        f32x4 eNew;
        if (s + 2 < NSL)
            eNew = ntld4(eSrc + (s + 2) * KS);

        // ds_write E(s+1) (loaded at s-1; compiler auto-waits its vmcnt)
        if (s + 1 < NSL) {
            unsigned lo = bf16_2(eOld.x, eOld.y), hi = bf16_2(eOld.z, eOld.w);
            *reinterpret_cast<unsigned long long*>(
                sE + nxt * (BW * KS) + we * KS + kp * 4) =
                ((unsigned long long)hi << 32) | lo;
        }

        // compute slice s
        const unsigned short* sGc = sG + cur * (N_TAGS * KS);
        const unsigned short* sEc = sE + cur * (BW * KS);
        bf16x8 a[4], b[4];
        #pragma unroll
        for (int mt = 0; mt < 4; ++mt)
            a[mt] = *reinterpret_cast<const bf16x8*>(
                sGc + (v * 64 + mt * 16 + n) * KS + q * 8);
        #pragma unroll
        for (int wt = 0; wt < 4; ++wt)
            b[wt] = *reinterpret_cast<const bf16x8*>(
                sEc + (wt * 16 + n) * KS + q * 8);
        #pragma unroll
        for (int mt = 0; mt < 4; ++mt)
            #pragma unroll
            for (int wt = 0; wt < 4; ++wt)
                acc[mt][wt] = __builtin_amdgcn_mfma_f32_16x16x32_bf16(
                    a[mt], b[wt], acc[mt][wt], 0, 0, 0);

        // counted-wait barrier: retire Gt(s+1) DMAs, keep E(s+2) in flight
        if (s + 2 < NSL) {
            asm volatile("s_waitcnt vmcnt(1) lgkmcnt(0)\n\ts_barrier" ::: "memory");
        } else if (s + 1 < NSL) {
            asm volatile("s_waitcnt vmcnt(0) lgkmcnt(0)\n\ts_barrier" ::: "memory");
        }
        eOld = eNew;
        cur = nxt;
    }

    // ---- + cvec: tag = v*64 + mt*16 + 4q + r ----
    #pragma unroll
    for (int mt = 0; mt < 4; ++mt) {
        f32x4 c4 = *reinterpret_cast<const f32x4*>(cvec + v * 64 + mt * 16 + 4 * q);
        #pragma unroll
        for (int wt = 0; wt < 4; ++wt) acc[mt][wt] += c4;
    }

    // ---- per-word partial softmax (wave covers 64 tags x 64 words) ----
    float mx[4], sm[4];
    #pragma unroll
    for (int wt = 0; wt < 4; ++wt) {
        float m = -3.0e38f;
        #pragma unroll
        for (int mt = 0; mt < 4; ++mt)
            m = fmaxf(m, fmaxf(fmaxf(acc[mt][wt].x, acc[mt][wt].y),
                               fmaxf(acc[mt][wt].z, acc[mt][wt].w)));
        m = fmaxf(m, __shfl_xor(m, 16, 64));
        m = fmaxf(m, __shfl_xor(m, 32, 64));
        mx[wt] = m;
        float s = 0.f;
        #pragma unroll
        for (int mt = 0; mt < 4; ++mt)
            s += __expf(acc[mt][wt].x - m) + __expf(acc[mt][wt].y - m)
               + __expf(acc[mt][wt].z - m) + __expf(acc[mt][wt].w - m);
        s += __shfl_xor(s, 16, 64);
        s += __shfl_xor(s, 32, 64);
        sm[wt] = s;
    }
    if (q == 0) {
        #pragma unroll
        for (int wt = 0; wt < 4; ++wt) {
            sMx[v][wt * 16 + n] = mx[wt];
            sSm[v][wt * 16 + n] = sm[wt];
        }
    }
    __syncthreads();

    // ---- cross-wave combine + epilogue stores (normal, full-line bursts) ----
    #pragma unroll
    for (int wt = 0; wt < 4; ++wt) {
        const int wd = wt * 16 + n;
        float M = sMx[0][wd];
        #pragma unroll
        for (int u = 1; u < 8; ++u) M = fmaxf(M, sMx[u][wd]);
        float S = 0.f;
        #pragma unroll
        for (int u = 0; u < 8; ++u) S += sSm[u][wd] * __expf(sMx[u][wd] - M);
        const float neg = M + __logf(S);

        const size_t row = (size_t)(w0 + wd) * N_TAGS + v * 64 + 4 * q;
        #pragma unroll
        for (int mt = 0; mt < 4; ++mt) {
            f32x4 lp, pp;
            lp.x = acc[mt][wt].x - neg;  pp.x = __expf(lp.x);
            lp.y = acc[mt][wt].y - neg;  pp.y = __expf(lp.y);
            lp.z = acc[mt][wt].z - neg;  pp.z = __expf(lp.z);
            lp.w = acc[mt][wt].w - neg;  pp.w = __expf(lp.w);
            *reinterpret_cast<f32x4*>(out_logp + row + mt * 16) = lp;
            *reinterpret_cast<f32x4*>(out_p    + row + mt * 16) = pp;
        }
    }
}

extern "C" void kernel_launch(void* const* d_in, const int* in_sizes, int n_in,
                              void* d_out, int out_size, void* d_ws, size_t ws_size,
                              hipStream_t stream) {
    const float* tags_embed  = (const float*)d_in[0];
    const float* words_embed = (const float*)d_in[1];
    const float* tags_W      = (const float*)d_in[2];
    const float* tags_b      = (const float*)d_in[3];
    const float* words_W     = (const float*)d_in[4];
    const float* words_b     = (const float*)d_in[5];

    float* out_logp = (float*)d_out;
    float* out_p    = out_logp + (size_t)N_WORDS * N_TAGS;

    // ws: Tbf [512][128] bf16 | cvec [512] f32 | Wtbf [768][128] bf16 |
    //     GtSl [24][512][32] bf16
    unsigned short* Tbf  = (unsigned short*)d_ws;
    float*          cvec = (float*)(Tbf + (size_t)N_TAGS * MDIM);
    unsigned short* Wtbf = (unsigned short*)(cvec + N_TAGS);
    unsigned short* GtSl = Wtbf + (size_t)BDIM * MDIM;

    tags_kernel<<<N_TAGS, 128, 0, stream>>>(tags_embed, tags_W, tags_b, words_b, Tbf, cvec);
    wt_kernel<<<96, 256, 0, stream>>>(words_W, Wtbf);
    gt_kernel<<<384, 64, 0, stream>>>(Wtbf, Tbf, GtSl);
    main_kernel<<<N_WORDS / BW, 512, 0, stream>>>(
        words_embed, GtSl, cvec, out_logp, out_p);
}